// Round 12
// baseline (19.604 us; speedup 1.0000x reference)
//
#include <hip/hip_runtime.h>
#include <cfloat>

// Problem constants: B=32, C=256, L=512, N=1024, S=8
constexpr int Bc = 32;
constexpr int Cc = 256;
constexpr int Lc = 512;
constexpr int Nc = 1024;
constexpr int Sc = 8;

constexpr int CT      = 8;    // channels per block
constexpr int STRIDE  = 524;  // rowbuf stride: 524%32==12 -> head/tail bank groups 4*(3cl+q), spread
constexpr int LSTRIDE = 141;  // lvl1 stride: 141%32==13 (coprime) -> bank 13cl+q, ~2-way worst

typedef float f4 __attribute__((ext_vector_type(4)));

// masked max over chunk elements [lo, hi) (cndmask, no branch)
__device__ __forceinline__ float chunkmax(f4 v, int lo, int hi, float m) {
    float a0 = (lo <= 0 && 0 < hi) ? v.x : -FLT_MAX;
    float a1 = (lo <= 1 && 1 < hi) ? v.y : -FLT_MAX;
    float a2 = (lo <= 2 && 2 < hi) ? v.z : -FLT_MAX;
    float a3 = (lo <= 3 && 3 < hi) ? v.w : -FLT_MAX;
    return fmaxf(fmaxf(m, fmaxf(a0, a1)), fmaxf(a2, a3));
}

// Block = (batch b, 8-channel tile); 1024 blocks, 4/CU, 16 waves/CU.
// R11's deterministic skeleton + (1) rois packed into list (no per-item global
// loads), (2) coprime lvl1 stride (bank conflicts ~free), (3) 2-item ILP.
__global__ __launch_bounds__(256) void roi_pool_pyr4(
    const float* __restrict__ sentences,   // (B, C, L)
    const int*   __restrict__ rois,        // (N, 2)
    const int*   __restrict__ roi_idx,     // (N,)
    float*       __restrict__ out)         // (N, C, S)
{
    __shared__ __align__(16) float rowbuf[CT * STRIDE];   // 16,768 B
    __shared__ float lvl1[CT * LSTRIDE];                  //  4,512 B
    __shared__ int   list[Nc];                            //  4 KB: packed n|x1<<10|x2<<20
    __shared__ int   wcnt[16];

    const int bid  = blockIdx.x;           // 0..1023
    const int b    = bid >> 5;             // batch
    const int c0   = (bid & 31) * CT;      // channel tile base
    const int tid  = threadIdx.x;
    const int lane = tid & 63;
    const int w    = tid >> 6;             // wave 0..3

    // ---- ballot compaction scan; matching threads also fetch+pack rois ----
    int mypack[4], mypos[4];
    #pragma unroll
    for (int q = 0; q < 4; ++q) {
        const int i = q * 256 + tid;
        const int v = roi_idx[i];
        const unsigned long long mask = __ballot(v == b);
        mypos[q] = __popcll(mask & ((1ull << lane) - 1ull));
        if (v == b) {
            const int xx1 = rois[2 * i];       // scattered but only ~32/block, L2-hot,
            const int xx2 = rois[2 * i + 1];   // latency hidden under staging below
            mypack[q] = i | (xx1 << 10) | (xx2 << 20);   // n:10 | x1:10 | x2:10 (x2<=512)
        } else {
            mypack[q] = -1;
        }
        if (lane == 0) wcnt[q * 4 + w] = __popcll(mask);
    }

    // ---- staging: load -> ds_write in-loop + level-1 pyramid (proven) ----
    {
        const f4* src = (const f4*)(sentences + ((size_t)b * Cc + c0) * Lc);
        #pragma unroll
        for (int i = 0; i < (CT * Lc / 4) / 256; ++i) {   // 4 chunks/thread
            const int idx = tid + i * 256;                // 0..1023
            const int r   = idx >> 7;                     // row 0..7
            const int q   = idx & 127;                    // f4 slot
            f4 v = src[r * (Lc / 4) + q];                 // coalesced 1KB/wave
            *(f4*)(rowbuf + r * STRIDE + 4 * q) = v;      // aligned, conflict-free
            lvl1[r * LSTRIDE + q] = fmaxf(fmaxf(v.x, v.y), fmaxf(v.z, v.w));
        }
    }
    __syncthreads();   // wcnt + rowbuf + lvl1 visible

    // ---- deterministic prefix over wcnt (verbatim) ----
    int wb0 = 0, wb1 = 0, wb2 = 0, wb3 = 0, run = 0;
    #pragma unroll
    for (int t = 0; t < 16; ++t) {
        if (t == w)      wb0 = run;
        if (t == 4 + w)  wb1 = run;
        if (t == 8 + w)  wb2 = run;
        if (t == 12 + w) wb3 = run;
        run += wcnt[t];
    }
    const int m = run;                     // bucket size for batch b

    if (mypack[0] >= 0) list[wb0 + mypos[0]] = mypack[0];
    if (mypack[1] >= 0) list[wb1 + mypos[1]] = mypack[1];
    if (mypack[2] >= 0) list[wb2 + mypos[2]] = mypack[2];
    if (mypack[3] >= 0) list[wb3 + mypos[3]] = mypack[3];
    __syncthreads();   // list visible

    // ---- bin maxes: wave w handles items w, w+4, ...; 2 items in flight ----
    const int cl = lane >> 3;              // channel within tile 0..7
    const int j  = lane & 7;               // bin
    const float* row = rowbuf + cl * STRIDE;
    const float* lv  = lvl1 + cl * LSTRIDE;

    for (int i = w; i < m; i += 8) {
        const bool has2 = (i + 4) < m;     // wave-uniform guard
        const int v1 = list[i];
        const int v2 = has2 ? list[i + 4] : v1;

        const int n1 = v1 & 1023, x1a = (v1 >> 10) & 1023, x2a = v1 >> 20;
        const int n2 = v2 & 1023, x1b = (v2 >> 10) & 1023, x2b = v2 >> 20;
        const int lr1 = x2a - x1a, lr2 = x2b - x1b;

        const int s1 = x1a + ((j * lr1) >> 3);
        const int e1 = x1a + (((j + 1) * lr1 + Sc - 1) >> 3);
        const int s2 = x1b + ((j * lr2) >> 3);
        const int e2 = x1b + (((j + 1) * lr2 + Sc - 1) >> 3);

        const int qs1 = s1 >> 2, qe1 = e1 >> 2;
        const int qs2 = s2 >> 2, qe2 = e2 >> 2;

        // both heads issued up front (2 loads in flight)
        f4 h1 = *(const f4*)(row + 4 * qs1);
        f4 h2 = *(const f4*)(row + 4 * qs2);
        float mA = chunkmax(h1, s1 & 3, min(4, e1 - 4 * qs1), -FLT_MAX);
        float mB = chunkmax(h2, s2 & 3, min(4, e2 - 4 * qs2), -FLT_MAX);

        // interiors via lvl1 (coprime stride: ~conflict-free)
        for (int q = qs1 + 1; q < qe1; ++q) mA = fmaxf(mA, lv[q]);
        for (int q = qs2 + 1; q < qe2; ++q) mB = fmaxf(mB, lv[q]);

        // tails (partial end blocks)
        if ((e1 & 3) && qe1 > qs1) {
            f4 t1 = *(const f4*)(row + 4 * qe1);
            mA = chunkmax(t1, 0, e1 & 3, mA);
        }
        if ((e2 & 3) && qe2 > qs2) {
            f4 t2 = *(const f4*)(row + 4 * qe2);
            mB = chunkmax(t2, 0, e2 & 3, mB);
        }

        out[(size_t)n1 * (Cc * Sc) + (c0 + cl) * Sc + j] = mA;
        if (has2)
            out[(size_t)n2 * (Cc * Sc) + (c0 + cl) * Sc + j] = mB;
    }
}

extern "C" void kernel_launch(void* const* d_in, const int* in_sizes, int n_in,
                              void* d_out, int out_size, void* d_ws, size_t ws_size,
                              hipStream_t stream) {
    const float* sentences = (const float*)d_in[0];
    const int*   rois      = (const int*)d_in[1];
    const int*   roi_idx   = (const int*)d_in[2];
    float*       out       = (float*)d_out;

    roi_pool_pyr4<<<Bc * (Cc / CT), 256, 0, stream>>>(sentences, rois, roi_idx, out);
}